// Round 16
// baseline (180.220 us; speedup 1.0000x reference)
//
#include <hip/hip_runtime.h>
#include <hip/hip_bf16.h>
#include <stdint.h>

// DenseGraphAttentionHead N=8192, IN=512, OUT=256, ~50% dense int32 mask.
//
// Pipeline:
//   k_convert_w : W f32 -> bf16 chunked (16B chunk (kb,row) at kb*2048+row*8).
//   k_front     : FUSED k_mask + k_wh (bid%9==8 -> wh). mask: int32 ->
//                 bitmask bm[row][wj] via __ballot (coalesced stream). wh:
//                 Wh = nodes@W^T + b (mfma) -> WhL chunked bf16 +
//                 exp-factorization tables (lrelu lets exp factor):
//                 P = mask * (s1+s2>0 ? e^{s1}e^{s2} : e^{.2s1}e^{.2s2})
//                 sAC = [e^{s1} | e^{.2s1} | e^{-.2s1}] f32 (3rd row = pos-
//                 test threshold: s1+s2>0 <=> e^{.2s2} > e^{-.2s1});
//                 sPK[j] = u32 {bf16 e^{s2} hi | bf16 e^{.2s2} lo} (4B/j).
//   k_attn      : masked-softmax @ Wh. 24 waves/CU (was 16): wave = 16 rows
//                 x 128 cols -> acc 32 AGPR, ~80 regs total, (512,6) = 6
//                 waves/SIMD; LDS 52KB (ring-3 48K + PK 4K) -> 3 blocks/CU.
//                 Grid 128rt(64 rows) x 8jc = 1024 blocks; 8 waves = 4
//                 rowgroups(16) x 2 colhalves(128). R9-proven schedule:
//                 vmcnt(3) -> s_barrier -> issue W(u+2) (ring-3) -> compute
//                 (exp-free build, 8 MFMA, setprio) -> issue bm(u+2) into
//                 dual regset. bm words per-lane from global (L2/L3, 2-step
//                 lead). Never drains vmcnt to 0 in the loop.
//   k_comb      : out = sum_jc(pnum) / sum_jc(pden), 8 partials.
//
// MFMA conventions (verified R1-R15 on this problem):
//   A frag: lane&15 = m, k = (lane>>4)*8 + i ; B same per-lane k order
//   D: col = lane&15, row = (lane>>4)*4 + reg

#define NN 8192
#define IND 512
#define OUTD 256

typedef __attribute__((ext_vector_type(8))) short short8;
typedef __attribute__((ext_vector_type(4))) short short4v;
typedef __attribute__((ext_vector_type(4))) float f32x4;
typedef __attribute__((ext_vector_type(4))) unsigned int u32x4;

#define AS_GLOBAL __attribute__((address_space(1)))
#define AS_LDS __attribute__((address_space(3)))

static __device__ __forceinline__ short f2bf(float f) {
  return __builtin_bit_cast(short, __float2bfloat16(f));
}

extern "C" __global__ __launch_bounds__(256) void k_convert_w(
    const float* __restrict__ W, short* __restrict__ W2) {
  const int t = blockIdx.x * 256 + threadIdx.x;  // 16384 threads
  const int row = t >> 6, kb = t & 63;
  const float* src = W + row * IND + kb * 8;
  f32x4 x0 = *(const f32x4*)src;
  f32x4 x1 = *(const f32x4*)(src + 4);
  short8 o;
  o[0] = f2bf(x0[0]); o[1] = f2bf(x0[1]); o[2] = f2bf(x0[2]); o[3] = f2bf(x0[3]);
  o[4] = f2bf(x1[0]); o[5] = f2bf(x1[1]); o[6] = f2bf(x1[2]); o[7] = f2bf(x1[3]);
  *(short8*)(W2 + (size_t)kb * 2048 + row * 8) = o;
}

// Fused mask-conversion + Wh GEMM. 1152 blocks x 256 thr.
extern "C" __global__ __launch_bounds__(256, 2) void k_front(
    const int* __restrict__ mask, uint32_t* __restrict__ bm,
    const float* __restrict__ nodes, const short* __restrict__ W2,
    const float* __restrict__ Wb, const float* __restrict__ a1w,
    const float* __restrict__ a1b, const float* __restrict__ a2w,
    const float* __restrict__ a2b, short* __restrict__ WhL,
    float* __restrict__ sAC, uint32_t* __restrict__ sPK) {
  const int bid = blockIdx.x;
  const int tid = threadIdx.x;
  const int wv = tid >> 6, lane = tid & 63;

  if (bid % 9 != 8) {
    // ---- mask part: int32 -> bitmask, pure coalesced streaming ----
    const int mb = (bid / 9) * 8 + (bid % 9);  // [0,1024)
    const int gw = mb * 4 + wv;                // 4096 waves
    const size_t base = (size_t)gw * 16384;    // 64 iters x 256 ints
#pragma unroll 4
    for (int it = 0; it < 64; ++it) {
      const size_t ib = base + (size_t)it * 256;
      unsigned long long b0 = __ballot(mask[ib + lane] != 0);
      unsigned long long b1 = __ballot(mask[ib + 64 + lane] != 0);
      unsigned long long b2 = __ballot(mask[ib + 128 + lane] != 0);
      unsigned long long b3 = __ballot(mask[ib + 192 + lane] != 0);
      if (lane < 8) {
        unsigned long long s01 = (lane & 2) ? b1 : b0;
        unsigned long long s23 = (lane & 2) ? b3 : b2;
        unsigned long long sel = (lane & 4) ? s23 : s01;
        bm[ib / 32 + lane] = (uint32_t)(sel >> ((lane & 1) * 32));
      }
    }
    return;
  }

  // ---- wh part: Wh = nodes@W^T + b, 4 waves x 16 rows = 64 rows/block ----
  const int wb = bid / 9;  // [0,128)
  const int g = lane >> 4, m = lane & 15;
  const int rowbase = wb * 64 + wv * 16;

  f32x4 acc[16];
#pragma unroll
  for (int nf = 0; nf < 16; ++nf) acc[nf] = (f32x4){0.f, 0.f, 0.f, 0.f};

  const float* arow = nodes + (size_t)(rowbase + m) * IND;
  const short* bb = W2 + (size_t)g * 2048 + m * 8;
#pragma unroll 4
  for (int k0 = 0; k0 < IND; k0 += 32) {
    const float* ap = arow + k0 + g * 8;
    f32x4 x0 = *(const f32x4*)ap;
    f32x4 x1 = *(const f32x4*)(ap + 4);
    short8 af;
    af[0] = f2bf(x0[0]); af[1] = f2bf(x0[1]); af[2] = f2bf(x0[2]); af[3] = f2bf(x0[3]);
    af[4] = f2bf(x1[0]); af[5] = f2bf(x1[1]); af[6] = f2bf(x1[2]); af[7] = f2bf(x1[3]);
    const short* bk = bb + (size_t)(k0 >> 3) * 2048;
#pragma unroll
    for (int nf = 0; nf < 16; ++nf) {
      short8 bf = *(const short8*)(bk + nf * 128);
      acc[nf] = __builtin_amdgcn_mfma_f32_16x16x32_bf16(af, bf, acc[nf], 0, 0, 0);
    }
  }

  float p1[4] = {0.f, 0.f, 0.f, 0.f}, p2[4] = {0.f, 0.f, 0.f, 0.f};
#pragma unroll
  for (int nf = 0; nf < 16; ++nf) {
    const int n = nf * 16 + m;
    const float b = Wb[n], c1 = a1w[n], c2 = a2w[n];
#pragma unroll
    for (int r = 0; r < 4; ++r) {
      float v = acc[nf][r] + b;
      acc[nf][r] = v;
      p1[r] += c1 * v;
      p2[r] += c2 * v;
    }
  }
#pragma unroll
  for (int off = 1; off < 16; off <<= 1) {
#pragma unroll
    for (int r = 0; r < 4; ++r) {
      p1[r] += __shfl_xor(p1[r], off);
      p2[r] += __shfl_xor(p2[r], off);
    }
  }
  if (m == 0) {
    const float b1 = a1b[0], b2 = a2b[0];
#pragma unroll
    for (int r = 0; r < 4; ++r) {
      const int row = rowbase + g * 4 + r;
      const float v1 = p1[r] + b1, v2 = p2[r] + b2;
      sAC[row] = __expf(v1);
      sAC[NN + row] = __expf(0.2f * v1);
      sAC[2 * NN + row] = __expf(-0.2f * v1);  // pos-test threshold
      const float B = __expf(v2), D = __expf(0.2f * v2);
      sPK[row] = ((uint32_t)(uint16_t)f2bf(B) << 16) | (uint16_t)f2bf(D);
    }
  }

  const size_t cbase = ((size_t)(rowbase >> 3) + (g >> 1)) * 2048 + (g & 1) * 4;
#pragma unroll
  for (int nf = 0; nf < 16; ++nf) {
    short4v o;
#pragma unroll
    for (int r = 0; r < 4; ++r) o[r] = f2bf(acc[nf][r]);
    *(short4v*)(WhL + cbase + (size_t)(nf * 16 + m) * 8) = o;
  }
}

extern "C" __global__ __launch_bounds__(512, 6) void k_attn(
    const uint32_t* __restrict__ bm, const short* __restrict__ WhL,
    const float* __restrict__ sAC, const uint32_t* __restrict__ sPK,
    float* __restrict__ pnum, float* __restrict__ pden) {
  // LDS: [0,49152) 3-slice WhL ring; [49152,53248) PK (4B/j x 1024 j)
  __shared__ char smem[53248];
  uint32_t* PKs = (uint32_t*)(smem + 49152);

  const int tid = threadIdx.x;
  const int w = tid >> 6, lane = tid & 63, g = lane >> 4, m = lane & 15;
  const int rt = blockIdx.x >> 3, jc = blockIdx.x & 7;
  const int rg = w & 3, ns = w >> 2;
  const int rb = rt * 64 + rg * 16;

  // per-lane row constants (single row rb+m)
  const float A0   = sAC[rb + m];           // e^{s1}
  const float C0   = sAC[NN + rb + m];      // e^{0.2 s1}
  const float invC = sAC[2 * NN + rb + m];  // e^{-0.2 s1}

  f32x4 acc[8];
#pragma unroll
  for (int nf = 0; nf < 8; ++nf) acc[nf] = (f32x4){0.f, 0.f, 0.f, 0.f};
  float den = 0.f;

  const uint32_t* bw = bm + (size_t)(rb + m) * 256 + jc * 32;
  const short* gS = WhL + (size_t)jc * 262144;

  // ---- prologue: bm(0),bm(1) regs; PK; W slices 0,1 -> ring bufs 0,1 ----
  uint32_t cwA = bw[0];
  uint32_t cwB = bw[1];
  if (tid < 256) {
    __builtin_amdgcn_global_load_lds(
        (const AS_GLOBAL void*)((const char*)sPK + (size_t)jc * 4096 + tid * 16),
        (AS_LDS void*)(smem + 49152 + tid * 16), 16, 0, 0);
  }
#pragma unroll
  for (int s = 0; s < 2; ++s) {
    const short* gsl = gS + s * 8192 + tid * 8;
    char* dst = smem + s * 16384 + tid * 16;
    __builtin_amdgcn_global_load_lds((const AS_GLOBAL void*)gsl,
                                     (AS_LDS void*)dst, 16, 0, 0);
    __builtin_amdgcn_global_load_lds((const AS_GLOBAL void*)(gsl + 4096),
                                     (AS_LDS void*)(dst + 8192), 16, 0, 0);
  }
  asm volatile("s_waitcnt vmcnt(0)" ::: "memory");
  __builtin_amdgcn_s_barrier();

  // exp-free P build: PK word = {bf16 B=e^{s2} hi | bf16 D=e^{.2s2} lo};
  // pos <=> D > invC; val = pos ? B*A0 : D*C0; masked by bm bit.
  auto build = [&](uint32_t mbits, const u32x4& q0, const u32x4& q1) -> short8 {
    short8 af;
#pragma unroll
    for (int i = 0; i < 8; ++i) {
      const uint32_t pw = (i < 4) ? q0[i] : q1[i - 4];
      const float D = __builtin_bit_cast(float, pw << 16);
      const float B = __builtin_bit_cast(float, pw & 0xFFFF0000u);
      const bool pos = D > invC;
      const float val = pos ? B * A0 : D * C0;
      const float pv = ((mbits >> i) & 1u) ? val : 0.f;
      den += pv;
      af[i] = f2bf(pv);
    }
    return af;
  };

  // ---- main loop: ring-3, vmcnt(3), wait -> barrier -> issue -> compute ----
  // Outstanding at top of step u: [W(u)x2, bm(u), W(u+1)x2, bm(u+1)] = 6.
  // vmcnt(3) forces W(u)+bm(u) (2-step-old), leaves 3 newest in flight.
  auto body = [&](int u, uint32_t& cw) {
    asm volatile("s_waitcnt vmcnt(3)" ::: "memory");
    __builtin_amdgcn_s_barrier();
    __builtin_amdgcn_sched_barrier(0);
    // issue W slice u+2 into ring buf[(u+2)%3] (readers of that buf were
    // step u-1 -> retired by the barrier above; tail issues are dead-safe)
    {
      const int up = (u + 2 < 32) ? u + 2 : 31;
      const int bi = (u + 2) % 3;
      const short* gn = gS + up * 8192 + tid * 8;
      char* dst = smem + bi * 16384 + tid * 16;
      __builtin_amdgcn_global_load_lds((const AS_GLOBAL void*)gn,
                                       (AS_LDS void*)dst, 16, 0, 0);
      __builtin_amdgcn_global_load_lds((const AS_GLOBAL void*)(gn + 4096),
                                       (AS_LDS void*)(dst + 8192), 16, 0, 0);
    }
    // compute step u
    const uint32_t* pk = &PKs[u * 32 + g * 8];
    const u32x4 q0 = *(const u32x4*)(pk + 0);
    const u32x4 q1 = *(const u32x4*)(pk + 4);
    short8 af = build(cw >> (g * 8), q0, q1);
    const short* bl = (const short*)(smem + (u % 3) * 16384) +
                      g * 2048 + (ns * 128 + m) * 8;
    __builtin_amdgcn_s_setprio(1);
#pragma unroll
    for (int nf = 0; nf < 8; ++nf) {
      short8 bf = *(const short8*)(bl + nf * 128);
      acc[nf] = __builtin_amdgcn_mfma_f32_16x16x32_bf16(af, bf, acc[nf], 0, 0, 0);
    }
    __builtin_amdgcn_s_setprio(0);
    // issue bm word u+2 into the regset just consumed (2-step lead)
    {
      const int ub = (u + 2 < 32) ? u + 2 : 31;
      cw = bw[ub];
    }
  };

  for (int uu = 0; uu < 32; uu += 2) {
    body(uu, cwA);
    body(uu + 1, cwB);
  }

  // den reduce across the 4 k-groups: lanes end with den for row rb+(lane&15)
  den += __shfl_xor(den, 16);
  den += __shfl_xor(den, 32);
  if (ns == 0 && lane < 16) pden[jc * NN + rb + m] = den;

  // each wave owns its disjoint 16x128 tile of pnum[jc]
  float* pn = pnum + (size_t)jc * NN * OUTD + (size_t)rb * OUTD + ns * 128;
#pragma unroll
  for (int r = 0; r < 4; ++r) {
    const int q = g * 4 + r;
#pragma unroll
    for (int nf = 0; nf < 8; ++nf) {
      pn[(size_t)q * OUTD + nf * 16 + m] = acc[nf][r];
    }
  }
}

extern "C" __global__ __launch_bounds__(256) void k_comb(
    const float* __restrict__ pnum, const float* __restrict__ pden,
    float* __restrict__ out) {
  const int idx = blockIdx.x * 256 + threadIdx.x;  // 524288 threads
  const int row = idx >> 6, c4 = (idx & 63) * 4;
  f32x4 s = (f32x4){0.f, 0.f, 0.f, 0.f};
  float d = 0.f;
#pragma unroll
  for (int jc = 0; jc < 8; ++jc) {
    f32x4 v = *(const f32x4*)(pnum + ((size_t)jc * NN + row) * OUTD + c4);
    s += v;
    d += pden[jc * NN + row];
  }
  const float inv = 1.f / d;
  *(f32x4*)(out + (size_t)row * OUTD + c4) = s * inv;
}

extern "C" void kernel_launch(void* const* d_in, const int* in_sizes, int n_in,
                              void* d_out, int out_size, void* d_ws, size_t ws_size,
                              hipStream_t stream) {
  const float* nodes = (const float*)d_in[0];
  const int*   mask  = (const int*)d_in[1];
  const float* W_w   = (const float*)d_in[2];
  const float* W_b   = (const float*)d_in[3];
  const float* a1w   = (const float*)d_in[4];
  const float* a1b   = (const float*)d_in[5];
  const float* a2w   = (const float*)d_in[6];
  const float* a2b   = (const float*)d_in[7];
  float* out = (float*)d_out;

  char* ws = (char*)d_ws;
  short*    WhL  = (short*)(ws);                                    // 4 MiB
  short*    W2   = (short*)(ws + (size_t)4  * 1024 * 1024 + 65536); // 256 KiB
  uint32_t* bmp  = (uint32_t*)(ws + (size_t)5  * 1024 * 1024);      // 8 MiB
  float*    sAC  = (float*)(ws + (size_t)13 * 1024 * 1024);         // 96 KiB
  uint32_t* sPK  = (uint32_t*)(ws + (size_t)14 * 1024 * 1024);      // 32 KiB
  float*    pnum = (float*)(ws + (size_t)16 * 1024 * 1024);         // 64 MiB
  float*    pden = (float*)(ws + (size_t)96 * 1024 * 1024);         // 256 KiB

  hipLaunchKernelGGL(k_convert_w, dim3(64), dim3(256), 0, stream, W_w, W2);
  hipLaunchKernelGGL(k_front, dim3(1152), dim3(256), 0, stream,
                     mask, bmp, nodes, W2, W_b, a1w, a1b, a2w, a2b,
                     WhL, sAC, sPK);
  hipLaunchKernelGGL(k_attn, dim3(1024), dim3(512), 0, stream,
                     bmp, WhL, sAC, sPK, pnum, pden);
  hipLaunchKernelGGL(k_comb, dim3(2048), dim3(256), 0, stream,
                     pnum, pden, out);
}

// Round 17
// 169.726 us; speedup vs baseline: 1.0618x; 1.0618x over previous
//
#include <hip/hip_runtime.h>
#include <hip/hip_bf16.h>
#include <stdint.h>

// DenseGraphAttentionHead N=8192, IN=512, OUT=256, ~50% dense int32 mask.
//
// Pipeline:
//   k_convert_w : W f32 -> bf16 chunked (16B chunk (kb,row) at kb*2048+row*8).
//   k_front     : FUSED k_mask + k_wh (bid%9==8 -> wh). mask: int32 ->
//                 bitmask bm[row][wj] via __ballot (coalesced stream). wh:
//                 Wh = nodes@W^T + b (mfma) -> WhL chunked bf16 + tables.
//                 MAX-IDENTITY (exact): exp(lrelu(s1+s2)) = max(e^{s1}e^{s2},
//                 e^{.2s1}e^{.2s2}) -> no compare/selects in the inner build.
//                 sAC = [A=e^{s1} | C=e^{.2s1}] f32;
//                 sPK[j] = u32 {bf16 B=e^{s2} hi | bf16 D=e^{.2s2} lo} (4B/j,
//                 bf16-PK proven in R16: absmax unchanged 4.88e-4).
//   k_attn      : R9-proven geometry/schedule: BM=128, grid 64rt x 8jc = 512
//                 blocks (2/CU); 8 waves = 4 rowgroups(32) x 2 colhalves;
//                 acc 64 AGPR; 3-slice LDS ring + counted vmcnt(2) + raw
//                 s_barrier; bm XOR-swizzled in LDS; PK (4KB) in LDS.
//                 Build: val = max(A*B, C*D) -> ~7 VALU/elem (was ~11).
//   k_comb      : out = sum_jc(pnum) / sum_jc(pden), 8 partials.
//
// MFMA conventions (verified R1-R16 on this problem):
//   A frag: lane&15 = m, k = (lane>>4)*8 + i ; B same per-lane k order
//   D: col = lane&15, row = (lane>>4)*4 + reg

#define NN 8192
#define IND 512
#define OUTD 256

typedef __attribute__((ext_vector_type(8))) short short8;
typedef __attribute__((ext_vector_type(4))) short short4v;
typedef __attribute__((ext_vector_type(4))) float f32x4;
typedef __attribute__((ext_vector_type(4))) unsigned int u32x4;

#define AS_GLOBAL __attribute__((address_space(1)))
#define AS_LDS __attribute__((address_space(3)))

static __device__ __forceinline__ short f2bf(float f) {
  return __builtin_bit_cast(short, __float2bfloat16(f));
}

extern "C" __global__ __launch_bounds__(256) void k_convert_w(
    const float* __restrict__ W, short* __restrict__ W2) {
  const int t = blockIdx.x * 256 + threadIdx.x;  // 16384 threads
  const int row = t >> 6, kb = t & 63;
  const float* src = W + row * IND + kb * 8;
  f32x4 x0 = *(const f32x4*)src;
  f32x4 x1 = *(const f32x4*)(src + 4);
  short8 o;
  o[0] = f2bf(x0[0]); o[1] = f2bf(x0[1]); o[2] = f2bf(x0[2]); o[3] = f2bf(x0[3]);
  o[4] = f2bf(x1[0]); o[5] = f2bf(x1[1]); o[6] = f2bf(x1[2]); o[7] = f2bf(x1[3]);
  *(short8*)(W2 + (size_t)kb * 2048 + row * 8) = o;
}

// Fused mask-conversion + Wh GEMM. 1152 blocks x 256 thr.
extern "C" __global__ __launch_bounds__(256, 2) void k_front(
    const int* __restrict__ mask, uint32_t* __restrict__ bm,
    const float* __restrict__ nodes, const short* __restrict__ W2,
    const float* __restrict__ Wb, const float* __restrict__ a1w,
    const float* __restrict__ a1b, const float* __restrict__ a2w,
    const float* __restrict__ a2b, short* __restrict__ WhL,
    float* __restrict__ sAC, uint32_t* __restrict__ sPK) {
  const int bid = blockIdx.x;
  const int tid = threadIdx.x;
  const int wv = tid >> 6, lane = tid & 63;

  if (bid % 9 != 8) {
    // ---- mask part: int32 -> bitmask, pure coalesced streaming ----
    const int mb = (bid / 9) * 8 + (bid % 9);  // [0,1024)
    const int gw = mb * 4 + wv;                // 4096 waves
    const size_t base = (size_t)gw * 16384;    // 64 iters x 256 ints
#pragma unroll 4
    for (int it = 0; it < 64; ++it) {
      const size_t ib = base + (size_t)it * 256;
      unsigned long long b0 = __ballot(mask[ib + lane] != 0);
      unsigned long long b1 = __ballot(mask[ib + 64 + lane] != 0);
      unsigned long long b2 = __ballot(mask[ib + 128 + lane] != 0);
      unsigned long long b3 = __ballot(mask[ib + 192 + lane] != 0);
      if (lane < 8) {
        unsigned long long s01 = (lane & 2) ? b1 : b0;
        unsigned long long s23 = (lane & 2) ? b3 : b2;
        unsigned long long sel = (lane & 4) ? s23 : s01;
        bm[ib / 32 + lane] = (uint32_t)(sel >> ((lane & 1) * 32));
      }
    }
    return;
  }

  // ---- wh part: Wh = nodes@W^T + b, 4 waves x 16 rows = 64 rows/block ----
  const int wb = bid / 9;  // [0,128)
  const int g = lane >> 4, m = lane & 15;
  const int rowbase = wb * 64 + wv * 16;

  f32x4 acc[16];
#pragma unroll
  for (int nf = 0; nf < 16; ++nf) acc[nf] = (f32x4){0.f, 0.f, 0.f, 0.f};

  const float* arow = nodes + (size_t)(rowbase + m) * IND;
  const short* bb = W2 + (size_t)g * 2048 + m * 8;
#pragma unroll 4
  for (int k0 = 0; k0 < IND; k0 += 32) {
    const float* ap = arow + k0 + g * 8;
    f32x4 x0 = *(const f32x4*)ap;
    f32x4 x1 = *(const f32x4*)(ap + 4);
    short8 af;
    af[0] = f2bf(x0[0]); af[1] = f2bf(x0[1]); af[2] = f2bf(x0[2]); af[3] = f2bf(x0[3]);
    af[4] = f2bf(x1[0]); af[5] = f2bf(x1[1]); af[6] = f2bf(x1[2]); af[7] = f2bf(x1[3]);
    const short* bk = bb + (size_t)(k0 >> 3) * 2048;
#pragma unroll
    for (int nf = 0; nf < 16; ++nf) {
      short8 bf = *(const short8*)(bk + nf * 128);
      acc[nf] = __builtin_amdgcn_mfma_f32_16x16x32_bf16(af, bf, acc[nf], 0, 0, 0);
    }
  }

  float p1[4] = {0.f, 0.f, 0.f, 0.f}, p2[4] = {0.f, 0.f, 0.f, 0.f};
#pragma unroll
  for (int nf = 0; nf < 16; ++nf) {
    const int n = nf * 16 + m;
    const float b = Wb[n], c1 = a1w[n], c2 = a2w[n];
#pragma unroll
    for (int r = 0; r < 4; ++r) {
      float v = acc[nf][r] + b;
      acc[nf][r] = v;
      p1[r] += c1 * v;
      p2[r] += c2 * v;
    }
  }
#pragma unroll
  for (int off = 1; off < 16; off <<= 1) {
#pragma unroll
    for (int r = 0; r < 4; ++r) {
      p1[r] += __shfl_xor(p1[r], off);
      p2[r] += __shfl_xor(p2[r], off);
    }
  }
  if (m == 0) {
    const float b1 = a1b[0], b2 = a2b[0];
#pragma unroll
    for (int r = 0; r < 4; ++r) {
      const int row = rowbase + g * 4 + r;
      const float v1 = p1[r] + b1, v2 = p2[r] + b2;
      sAC[row] = __expf(v1);             // A = e^{s1}
      sAC[NN + row] = __expf(0.2f * v1); // C = e^{0.2 s1}
      const float B = __expf(v2), D = __expf(0.2f * v2);
      sPK[row] = ((uint32_t)(uint16_t)f2bf(B) << 16) | (uint16_t)f2bf(D);
    }
  }

  const size_t cbase = ((size_t)(rowbase >> 3) + (g >> 1)) * 2048 + (g & 1) * 4;
#pragma unroll
  for (int nf = 0; nf < 16; ++nf) {
    short4v o;
#pragma unroll
    for (int r = 0; r < 4; ++r) o[r] = f2bf(acc[nf][r]);
    *(short4v*)(WhL + cbase + (size_t)(nf * 16 + m) * 8) = o;
  }
}

extern "C" __global__ __launch_bounds__(512, 4) void k_attn(
    const uint32_t* __restrict__ bm, const short* __restrict__ WhL,
    const float* __restrict__ sAC, const uint32_t* __restrict__ sPK,
    float* __restrict__ pnum, float* __restrict__ pden) {
  // LDS: [0,49152) 3-slice WhL ring; [49152,53248) PK (4B/j);
  //      [53248,69632) bm words (128 rows x 32 words, XOR-swizzled)
  __shared__ char smem[69632];
  uint32_t* PKs = (uint32_t*)(smem + 49152);
  uint32_t* BMs = (uint32_t*)(smem + 53248);

  const int tid = threadIdx.x;
  const int w = tid >> 6, lane = tid & 63, g = lane >> 4, m = lane & 15;
  const int rt = blockIdx.x >> 3, jc = blockIdx.x & 7;
  const int rg = w & 3, ns = w >> 2;
  const int rb = rt * 128 + rg * 32;

  const float A0 = sAC[rb + m],      A1 = sAC[rb + 16 + m];
  const float C0 = sAC[NN + rb + m], C1 = sAC[NN + rb + 16 + m];

  f32x4 acc0[8], acc1[8];
#pragma unroll
  for (int nf = 0; nf < 8; ++nf) {
    acc0[nf] = (f32x4){0.f, 0.f, 0.f, 0.f};
    acc1[nf] = (f32x4){0.f, 0.f, 0.f, 0.f};
  }
  float den0 = 0.f, den1 = 0.f;

  // ---- prologue ----
  // bm slice (128 rows x 32 words), XOR-swizzled
  {
    const int rloc = tid >> 2, wq = (tid & 3) * 8;
    const uint32_t* src = bm + (size_t)(rt * 128 + rloc) * 256 + jc * 32 + wq;
    u32x4 a = *(const u32x4*)src;
    u32x4 b = *(const u32x4*)(src + 4);
#pragma unroll
    for (int i = 0; i < 4; ++i)
      BMs[rloc * 32 + ((wq + i) ^ (rloc & 31))] = a[i];
#pragma unroll
    for (int i = 0; i < 4; ++i)
      BMs[rloc * 32 + ((wq + 4 + i) ^ (rloc & 31))] = b[i];
  }
  // PK slice (4 KB): 256 threads x 16 B
  if (tid < 256) {
    __builtin_amdgcn_global_load_lds(
        (const AS_GLOBAL void*)((const char*)sPK + (size_t)jc * 4096 + tid * 16),
        (AS_LDS void*)(smem + 49152 + tid * 16), 16, 0, 0);
  }
  // WhL slices 0 and 1 into ring bufs 0,1
  const short* gS = WhL + (size_t)jc * 262144;
#pragma unroll
  for (int s = 0; s < 2; ++s) {
#pragma unroll
    for (int c = 0; c < 2; ++c) {
      __builtin_amdgcn_global_load_lds(
          (const AS_GLOBAL void*)(gS + s * 8192 + w * 1024 + c * 512 + lane * 8),
          (AS_LDS void*)(smem + s * 16384 + w * 2048 + c * 1024), 16, 0, 0);
    }
  }
  __syncthreads();  // drains prologue loads (vmcnt ledger resets to 0)

  // exp-free, branch-free build: val = max(A*B, C*D) == exp(lrelu(s1+s2))
  auto build = [&](float A, float C, uint32_t mbits,
                   const u32x4& q0, const u32x4& q1, float& den) -> short8 {
    short8 af;
#pragma unroll
    for (int i = 0; i < 8; ++i) {
      const uint32_t pw = (i < 4) ? q0[i] : q1[i - 4];
      const float D = __builtin_bit_cast(float, pw << 16);
      const float B = __builtin_bit_cast(float, pw & 0xFFFF0000u);
      const float val = fmaxf(A * B, C * D);
      const float pv = ((mbits >> i) & 1u) ? val : 0.f;
      den += pv;
      af[i] = f2bf(pv);
    }
    return af;
  };

  // ---- main loop: ring-3, counted vmcnt(2), one barrier/step ----
  for (int u = 0; u < 32; ++u) {
    asm volatile("s_waitcnt vmcnt(2)" ::: "memory");
    __builtin_amdgcn_s_barrier();
    __builtin_amdgcn_sched_barrier(0);

    // issue slice u+2 into buf[(u+2)%3]
    {
      const int up = (u + 2 < 32) ? (u + 2) : 31;
      const int bi = (u + 2) % 3;
      const short* gn = gS + up * 8192 + w * 1024 + lane * 8;
      char* ldb = smem + bi * 16384 + w * 2048;
      __builtin_amdgcn_global_load_lds((const AS_GLOBAL void*)gn,
                                       (AS_LDS void*)ldb, 16, 0, 0);
      __builtin_amdgcn_global_load_lds((const AS_GLOBAL void*)(gn + 512),
                                       (AS_LDS void*)(ldb + 1024), 16, 0, 0);
    }

    const uint32_t cw0 = BMs[(rg * 32 + m) * 32 + (u ^ m)];
    const uint32_t cw1 = BMs[(rg * 32 + 16 + m) * 32 + (u ^ (16 + m))];
    const uint32_t* pk = &PKs[u * 32 + g * 8];
    const u32x4 q0 = *(const u32x4*)(pk + 0);
    const u32x4 q1 = *(const u32x4*)(pk + 4);
    short8 af0 = build(A0, C0, cw0 >> (g * 8), q0, q1, den0);
    short8 af1 = build(A1, C1, cw1 >> (g * 8), q0, q1, den1);

    const short* bl = (const short*)(smem + (u % 3) * 16384) +
                      g * 2048 + (ns * 128 + m) * 8;
#pragma unroll
    for (int nf = 0; nf < 8; ++nf) {
      short8 bf = *(const short8*)(bl + nf * 128);
      acc0[nf] = __builtin_amdgcn_mfma_f32_16x16x32_bf16(af0, bf, acc0[nf], 0, 0, 0);
      acc1[nf] = __builtin_amdgcn_mfma_f32_16x16x32_bf16(af1, bf, acc1[nf], 0, 0, 0);
    }
  }

  den0 += __shfl_xor(den0, 16); den0 += __shfl_xor(den0, 32);
  den1 += __shfl_xor(den1, 16); den1 += __shfl_xor(den1, 32);
  if (ns == 0 && lane < 16) {
    pden[jc * NN + rb + m] = den0;
    pden[jc * NN + rb + 16 + m] = den1;
  }

  float* pn = pnum + (size_t)jc * NN * OUTD + (size_t)rb * OUTD + ns * 128;
#pragma unroll
  for (int r = 0; r < 4; ++r) {
    const int q = g * 4 + r;
#pragma unroll
    for (int nf = 0; nf < 8; ++nf) {
      pn[(size_t)q * OUTD + nf * 16 + m] = acc0[nf][r];
      pn[(size_t)(16 + q) * OUTD + nf * 16 + m] = acc1[nf][r];
    }
  }
}

extern "C" __global__ __launch_bounds__(256) void k_comb(
    const float* __restrict__ pnum, const float* __restrict__ pden,
    float* __restrict__ out) {
  const int idx = blockIdx.x * 256 + threadIdx.x;  // 524288 threads
  const int row = idx >> 6, c4 = (idx & 63) * 4;
  f32x4 s = (f32x4){0.f, 0.f, 0.f, 0.f};
  float d = 0.f;
#pragma unroll
  for (int jc = 0; jc < 8; ++jc) {
    f32x4 v = *(const f32x4*)(pnum + ((size_t)jc * NN + row) * OUTD + c4);
    s += v;
    d += pden[jc * NN + row];
  }
  const float inv = 1.f / d;
  *(f32x4*)(out + (size_t)row * OUTD + c4) = s * inv;
}

extern "C" void kernel_launch(void* const* d_in, const int* in_sizes, int n_in,
                              void* d_out, int out_size, void* d_ws, size_t ws_size,
                              hipStream_t stream) {
  const float* nodes = (const float*)d_in[0];
  const int*   mask  = (const int*)d_in[1];
  const float* W_w   = (const float*)d_in[2];
  const float* W_b   = (const float*)d_in[3];
  const float* a1w   = (const float*)d_in[4];
  const float* a1b   = (const float*)d_in[5];
  const float* a2w   = (const float*)d_in[6];
  const float* a2b   = (const float*)d_in[7];
  float* out = (float*)d_out;

  char* ws = (char*)d_ws;
  short*    WhL  = (short*)(ws);                                    // 4 MiB
  short*    W2   = (short*)(ws + (size_t)4  * 1024 * 1024 + 65536); // 256 KiB
  uint32_t* bmp  = (uint32_t*)(ws + (size_t)5  * 1024 * 1024);      // 8 MiB
  float*    sAC  = (float*)(ws + (size_t)13 * 1024 * 1024);         // 64 KiB
  uint32_t* sPK  = (uint32_t*)(ws + (size_t)14 * 1024 * 1024);      // 32 KiB
  float*    pnum = (float*)(ws + (size_t)16 * 1024 * 1024);         // 64 MiB
  float*    pden = (float*)(ws + (size_t)96 * 1024 * 1024);         // 256 KiB

  hipLaunchKernelGGL(k_convert_w, dim3(64), dim3(256), 0, stream, W_w, W2);
  hipLaunchKernelGGL(k_front, dim3(1152), dim3(256), 0, stream,
                     mask, bmp, nodes, W2, W_b, a1w, a1b, a2w, a2b,
                     WhL, sAC, sPK);
  hipLaunchKernelGGL(k_attn, dim3(512), dim3(512), 0, stream,
                     bmp, WhL, sAC, sPK, pnum, pden);
  hipLaunchKernelGGL(k_comb, dim3(2048), dim3(256), 0, stream,
                     pnum, pden, out);
}

// Round 18
// 169.396 us; speedup vs baseline: 1.0639x; 1.0019x over previous
//
#include <hip/hip_runtime.h>
#include <hip/hip_bf16.h>
#include <stdint.h>

// DenseGraphAttentionHead N=8192, IN=512, OUT=256, ~50% dense int32 mask.
//
// Pipeline:
//   k_convert_w : W f32 -> bf16 chunked (16B chunk (kb,row) at kb*2048+row*8).
//   k_front     : FUSED k_mask + k_wh (bid%9==8 -> wh). mask: int32 ->
//                 bitmask bm[row][wj] via __ballot (coalesced stream). wh:
//                 Wh = nodes@W^T + b (mfma) -> WhL chunked bf16 + tables.
//                 MAX-IDENTITY (exact): exp(lrelu(s1+s2)) = max(e^{s1}e^{s2},
//                 e^{.2s1}e^{.2s2}).
//                 sAC = [A=e^{s1} | C=e^{.2s1}] f32;
//                 sPK[j] = u32 {bf16 B=e^{s2} hi | bf16 D=e^{.2s2} lo}.
//   k_attn      : R17 + PER-BLOCK PHASE ROTATION of the j-step order (step u
//                 processes window v=(phase+u)&31). De-phases the two
//                 co-resident blocks per CU so their barrier-drain windows
//                 interleave instead of aligning (the ~3x step-stall factor
//                 resisted every pipelining attack; this targets its last
//                 untested mechanism). phase = ((bid>>6)*5+bid)&31 chosen so
//                 likely co-resident pairs (dbid=256) get dphase=20. Ring-3 /
//                 vmcnt(2) ledger unchanged (only data addressing rotates).
//                 + s_setprio(1) around the MFMA cluster (T5 - de-phased
//                 blocks create the role diversity setprio needs).
//   k_comb      : out = sum_jc(pnum) / sum_jc(pden), 8 partials.
//
// MFMA conventions (verified R1-R17 on this problem):
//   A frag: lane&15 = m, k = (lane>>4)*8 + i ; B same per-lane k order
//   D: col = lane&15, row = (lane>>4)*4 + reg

#define NN 8192
#define IND 512
#define OUTD 256

typedef __attribute__((ext_vector_type(8))) short short8;
typedef __attribute__((ext_vector_type(4))) short short4v;
typedef __attribute__((ext_vector_type(4))) float f32x4;
typedef __attribute__((ext_vector_type(4))) unsigned int u32x4;

#define AS_GLOBAL __attribute__((address_space(1)))
#define AS_LDS __attribute__((address_space(3)))

static __device__ __forceinline__ short f2bf(float f) {
  return __builtin_bit_cast(short, __float2bfloat16(f));
}

extern "C" __global__ __launch_bounds__(256) void k_convert_w(
    const float* __restrict__ W, short* __restrict__ W2) {
  const int t = blockIdx.x * 256 + threadIdx.x;  // 16384 threads
  const int row = t >> 6, kb = t & 63;
  const float* src = W + row * IND + kb * 8;
  f32x4 x0 = *(const f32x4*)src;
  f32x4 x1 = *(const f32x4*)(src + 4);
  short8 o;
  o[0] = f2bf(x0[0]); o[1] = f2bf(x0[1]); o[2] = f2bf(x0[2]); o[3] = f2bf(x0[3]);
  o[4] = f2bf(x1[0]); o[5] = f2bf(x1[1]); o[6] = f2bf(x1[2]); o[7] = f2bf(x1[3]);
  *(short8*)(W2 + (size_t)kb * 2048 + row * 8) = o;
}

// Fused mask-conversion + Wh GEMM. 1152 blocks x 256 thr.
extern "C" __global__ __launch_bounds__(256, 2) void k_front(
    const int* __restrict__ mask, uint32_t* __restrict__ bm,
    const float* __restrict__ nodes, const short* __restrict__ W2,
    const float* __restrict__ Wb, const float* __restrict__ a1w,
    const float* __restrict__ a1b, const float* __restrict__ a2w,
    const float* __restrict__ a2b, short* __restrict__ WhL,
    float* __restrict__ sAC, uint32_t* __restrict__ sPK) {
  const int bid = blockIdx.x;
  const int tid = threadIdx.x;
  const int wv = tid >> 6, lane = tid & 63;

  if (bid % 9 != 8) {
    // ---- mask part: int32 -> bitmask, pure coalesced streaming ----
    const int mb = (bid / 9) * 8 + (bid % 9);  // [0,1024)
    const int gw = mb * 4 + wv;                // 4096 waves
    const size_t base = (size_t)gw * 16384;    // 64 iters x 256 ints
#pragma unroll 4
    for (int it = 0; it < 64; ++it) {
      const size_t ib = base + (size_t)it * 256;
      unsigned long long b0 = __ballot(mask[ib + lane] != 0);
      unsigned long long b1 = __ballot(mask[ib + 64 + lane] != 0);
      unsigned long long b2 = __ballot(mask[ib + 128 + lane] != 0);
      unsigned long long b3 = __ballot(mask[ib + 192 + lane] != 0);
      if (lane < 8) {
        unsigned long long s01 = (lane & 2) ? b1 : b0;
        unsigned long long s23 = (lane & 2) ? b3 : b2;
        unsigned long long sel = (lane & 4) ? s23 : s01;
        bm[ib / 32 + lane] = (uint32_t)(sel >> ((lane & 1) * 32));
      }
    }
    return;
  }

  // ---- wh part: Wh = nodes@W^T + b, 4 waves x 16 rows = 64 rows/block ----
  const int wb = bid / 9;  // [0,128)
  const int g = lane >> 4, m = lane & 15;
  const int rowbase = wb * 64 + wv * 16;

  f32x4 acc[16];
#pragma unroll
  for (int nf = 0; nf < 16; ++nf) acc[nf] = (f32x4){0.f, 0.f, 0.f, 0.f};

  const float* arow = nodes + (size_t)(rowbase + m) * IND;
  const short* bb = W2 + (size_t)g * 2048 + m * 8;
#pragma unroll 4
  for (int k0 = 0; k0 < IND; k0 += 32) {
    const float* ap = arow + k0 + g * 8;
    f32x4 x0 = *(const f32x4*)ap;
    f32x4 x1 = *(const f32x4*)(ap + 4);
    short8 af;
    af[0] = f2bf(x0[0]); af[1] = f2bf(x0[1]); af[2] = f2bf(x0[2]); af[3] = f2bf(x0[3]);
    af[4] = f2bf(x1[0]); af[5] = f2bf(x1[1]); af[6] = f2bf(x1[2]); af[7] = f2bf(x1[3]);
    const short* bk = bb + (size_t)(k0 >> 3) * 2048;
#pragma unroll
    for (int nf = 0; nf < 16; ++nf) {
      short8 bf = *(const short8*)(bk + nf * 128);
      acc[nf] = __builtin_amdgcn_mfma_f32_16x16x32_bf16(af, bf, acc[nf], 0, 0, 0);
    }
  }

  float p1[4] = {0.f, 0.f, 0.f, 0.f}, p2[4] = {0.f, 0.f, 0.f, 0.f};
#pragma unroll
  for (int nf = 0; nf < 16; ++nf) {
    const int n = nf * 16 + m;
    const float b = Wb[n], c1 = a1w[n], c2 = a2w[n];
#pragma unroll
    for (int r = 0; r < 4; ++r) {
      float v = acc[nf][r] + b;
      acc[nf][r] = v;
      p1[r] += c1 * v;
      p2[r] += c2 * v;
    }
  }
#pragma unroll
  for (int off = 1; off < 16; off <<= 1) {
#pragma unroll
    for (int r = 0; r < 4; ++r) {
      p1[r] += __shfl_xor(p1[r], off);
      p2[r] += __shfl_xor(p2[r], off);
    }
  }
  if (m == 0) {
    const float b1 = a1b[0], b2 = a2b[0];
#pragma unroll
    for (int r = 0; r < 4; ++r) {
      const int row = rowbase + g * 4 + r;
      const float v1 = p1[r] + b1, v2 = p2[r] + b2;
      sAC[row] = __expf(v1);             // A = e^{s1}
      sAC[NN + row] = __expf(0.2f * v1); // C = e^{0.2 s1}
      const float B = __expf(v2), D = __expf(0.2f * v2);
      sPK[row] = ((uint32_t)(uint16_t)f2bf(B) << 16) | (uint16_t)f2bf(D);
    }
  }

  const size_t cbase = ((size_t)(rowbase >> 3) + (g >> 1)) * 2048 + (g & 1) * 4;
#pragma unroll
  for (int nf = 0; nf < 16; ++nf) {
    short4v o;
#pragma unroll
    for (int r = 0; r < 4; ++r) o[r] = f2bf(acc[nf][r]);
    *(short4v*)(WhL + cbase + (size_t)(nf * 16 + m) * 8) = o;
  }
}

extern "C" __global__ __launch_bounds__(512, 4) void k_attn(
    const uint32_t* __restrict__ bm, const short* __restrict__ WhL,
    const float* __restrict__ sAC, const uint32_t* __restrict__ sPK,
    float* __restrict__ pnum, float* __restrict__ pden) {
  // LDS: [0,49152) 3-slice WhL ring; [49152,53248) PK (4B/j);
  //      [53248,69632) bm words (128 rows x 32 words, XOR-swizzled)
  __shared__ char smem[69632];
  uint32_t* PKs = (uint32_t*)(smem + 49152);
  uint32_t* BMs = (uint32_t*)(smem + 53248);

  const int tid = threadIdx.x;
  const int w = tid >> 6, lane = tid & 63, g = lane >> 4, m = lane & 15;
  const int rt = blockIdx.x >> 3, jc = blockIdx.x & 7;
  const int rg = w & 3, ns = w >> 2;
  const int rb = rt * 128 + rg * 32;
  // per-block step-phase: de-phases co-resident blocks' barrier convoys.
  // Likely co-resident pairs differ by 256 in bid -> dphase = 20 (!= 0).
  const int phase = (((int)blockIdx.x >> 6) * 5 + (int)blockIdx.x) & 31;

  const float A0 = sAC[rb + m],      A1 = sAC[rb + 16 + m];
  const float C0 = sAC[NN + rb + m], C1 = sAC[NN + rb + 16 + m];

  f32x4 acc0[8], acc1[8];
#pragma unroll
  for (int nf = 0; nf < 8; ++nf) {
    acc0[nf] = (f32x4){0.f, 0.f, 0.f, 0.f};
    acc1[nf] = (f32x4){0.f, 0.f, 0.f, 0.f};
  }
  float den0 = 0.f, den1 = 0.f;

  // ---- prologue ----
  // bm slice (128 rows x 32 words), XOR-swizzled
  {
    const int rloc = tid >> 2, wq = (tid & 3) * 8;
    const uint32_t* src = bm + (size_t)(rt * 128 + rloc) * 256 + jc * 32 + wq;
    u32x4 a = *(const u32x4*)src;
    u32x4 b = *(const u32x4*)(src + 4);
#pragma unroll
    for (int i = 0; i < 4; ++i)
      BMs[rloc * 32 + ((wq + i) ^ (rloc & 31))] = a[i];
#pragma unroll
    for (int i = 0; i < 4; ++i)
      BMs[rloc * 32 + ((wq + 4 + i) ^ (rloc & 31))] = b[i];
  }
  // PK slice (4 KB): 256 threads x 16 B
  if (tid < 256) {
    __builtin_amdgcn_global_load_lds(
        (const AS_GLOBAL void*)((const char*)sPK + (size_t)jc * 4096 + tid * 16),
        (AS_LDS void*)(smem + 49152 + tid * 16), 16, 0, 0);
  }
  // WhL windows v(0)=phase, v(1)=phase+1 into ring bufs 0,1
  const short* gS = WhL + (size_t)jc * 262144;
#pragma unroll
  for (int s = 0; s < 2; ++s) {
    const int vs = (phase + s) & 31;
#pragma unroll
    for (int c = 0; c < 2; ++c) {
      __builtin_amdgcn_global_load_lds(
          (const AS_GLOBAL void*)(gS + vs * 8192 + w * 1024 + c * 512 + lane * 8),
          (AS_LDS void*)(smem + s * 16384 + w * 2048 + c * 1024), 16, 0, 0);
    }
  }
  __syncthreads();  // drains prologue loads (vmcnt ledger resets to 0)

  // exp-free, branch-free build: val = max(A*B, C*D) == exp(lrelu(s1+s2))
  auto build = [&](float A, float C, uint32_t mbits,
                   const u32x4& q0, const u32x4& q1, float& den) -> short8 {
    short8 af;
#pragma unroll
    for (int i = 0; i < 8; ++i) {
      const uint32_t pw = (i < 4) ? q0[i] : q1[i - 4];
      const float D = __builtin_bit_cast(float, pw << 16);
      const float B = __builtin_bit_cast(float, pw & 0xFFFF0000u);
      const float val = fmaxf(A * B, C * D);
      const float pv = ((mbits >> i) & 1u) ? val : 0.f;
      den += pv;
      af[i] = f2bf(pv);
    }
    return af;
  };

  // ---- main loop: ring-3, counted vmcnt(2), one barrier/step ----
  // Step u computes j-window v = (phase+u)&31; ring index follows u.
  for (int u = 0; u < 32; ++u) {
    asm volatile("s_waitcnt vmcnt(2)" ::: "memory");
    __builtin_amdgcn_s_barrier();
    __builtin_amdgcn_sched_barrier(0);

    // issue window v(u+2) into buf[(u+2)%3] (wrap at tail: dead data, safe)
    {
      const int vp = (phase + u + 2) & 31;
      const int bi = (u + 2) % 3;
      const short* gn = gS + vp * 8192 + w * 1024 + lane * 8;
      char* ldb = smem + bi * 16384 + w * 2048;
      __builtin_amdgcn_global_load_lds((const AS_GLOBAL void*)gn,
                                       (AS_LDS void*)ldb, 16, 0, 0);
      __builtin_amdgcn_global_load_lds((const AS_GLOBAL void*)(gn + 512),
                                       (AS_LDS void*)(ldb + 1024), 16, 0, 0);
    }

    const int v = (phase + u) & 31;
    const uint32_t cw0 = BMs[(rg * 32 + m) * 32 + (v ^ m)];
    const uint32_t cw1 = BMs[(rg * 32 + 16 + m) * 32 + (v ^ (16 + m))];
    const uint32_t* pk = &PKs[v * 32 + g * 8];
    const u32x4 q0 = *(const u32x4*)(pk + 0);
    const u32x4 q1 = *(const u32x4*)(pk + 4);
    short8 af0 = build(A0, C0, cw0 >> (g * 8), q0, q1, den0);
    short8 af1 = build(A1, C1, cw1 >> (g * 8), q0, q1, den1);

    const short* bl = (const short*)(smem + (u % 3) * 16384) +
                      g * 2048 + (ns * 128 + m) * 8;
    __builtin_amdgcn_s_setprio(1);
#pragma unroll
    for (int nf = 0; nf < 8; ++nf) {
      short8 bf = *(const short8*)(bl + nf * 128);
      acc0[nf] = __builtin_amdgcn_mfma_f32_16x16x32_bf16(af0, bf, acc0[nf], 0, 0, 0);
      acc1[nf] = __builtin_amdgcn_mfma_f32_16x16x32_bf16(af1, bf, acc1[nf], 0, 0, 0);
    }
    __builtin_amdgcn_s_setprio(0);
  }

  den0 += __shfl_xor(den0, 16); den0 += __shfl_xor(den0, 32);
  den1 += __shfl_xor(den1, 16); den1 += __shfl_xor(den1, 32);
  if (ns == 0 && lane < 16) {
    pden[jc * NN + rb + m] = den0;
    pden[jc * NN + rb + 16 + m] = den1;
  }

  float* pn = pnum + (size_t)jc * NN * OUTD + (size_t)rb * OUTD + ns * 128;
#pragma unroll
  for (int r = 0; r < 4; ++r) {
    const int q = g * 4 + r;
#pragma unroll
    for (int nf = 0; nf < 8; ++nf) {
      pn[(size_t)q * OUTD + nf * 16 + m] = acc0[nf][r];
      pn[(size_t)(16 + q) * OUTD + nf * 16 + m] = acc1[nf][r];
    }
  }
}

extern "C" __global__ __launch_bounds__(256) void k_comb(
    const float* __restrict__ pnum, const float* __restrict__ pden,
    float* __restrict__ out) {
  const int idx = blockIdx.x * 256 + threadIdx.x;  // 524288 threads
  const int row = idx >> 6, c4 = (idx & 63) * 4;
  f32x4 s = (f32x4){0.f, 0.f, 0.f, 0.f};
  float d = 0.f;
#pragma unroll
  for (int jc = 0; jc < 8; ++jc) {
    f32x4 v = *(const f32x4*)(pnum + ((size_t)jc * NN + row) * OUTD + c4);
    s += v;
    d += pden[jc * NN + row];
  }
  const float inv = 1.f / d;
  *(f32x4*)(out + (size_t)row * OUTD + c4) = s * inv;
}

extern "C" void kernel_launch(void* const* d_in, const int* in_sizes, int n_in,
                              void* d_out, int out_size, void* d_ws, size_t ws_size,
                              hipStream_t stream) {
  const float* nodes = (const float*)d_in[0];
  const int*   mask  = (const int*)d_in[1];
  const float* W_w   = (const float*)d_in[2];
  const float* W_b   = (const float*)d_in[3];
  const float* a1w   = (const float*)d_in[4];
  const float* a1b   = (const float*)d_in[5];
  const float* a2w   = (const float*)d_in[6];
  const float* a2b   = (const float*)d_in[7];
  float* out = (float*)d_out;

  char* ws = (char*)d_ws;
  short*    WhL  = (short*)(ws);                                    // 4 MiB
  short*    W2   = (short*)(ws + (size_t)4  * 1024 * 1024 + 65536); // 256 KiB
  uint32_t* bmp  = (uint32_t*)(ws + (size_t)5  * 1024 * 1024);      // 8 MiB
  float*    sAC  = (float*)(ws + (size_t)13 * 1024 * 1024);         // 64 KiB
  uint32_t* sPK  = (uint32_t*)(ws + (size_t)14 * 1024 * 1024);      // 32 KiB
  float*    pnum = (float*)(ws + (size_t)16 * 1024 * 1024);         // 64 MiB
  float*    pden = (float*)(ws + (size_t)96 * 1024 * 1024);         // 256 KiB

  hipLaunchKernelGGL(k_convert_w, dim3(64), dim3(256), 0, stream, W_w, W2);
  hipLaunchKernelGGL(k_front, dim3(1152), dim3(256), 0, stream,
                     mask, bmp, nodes, W2, W_b, a1w, a1b, a2w, a2b,
                     WhL, sAC, sPK);
  hipLaunchKernelGGL(k_attn, dim3(512), dim3(512), 0, stream,
                     bmp, WhL, sAC, sPK, pnum, pden);
  hipLaunchKernelGGL(k_comb, dim3(2048), dim3(256), 0, stream,
                     pnum, pden, out);
}